// Round 2
// baseline (1093.200 us; speedup 1.0000x reference)
//
#include <hip/hip_runtime.h>
#include <hip/hip_cooperative_groups.h>
#include <math.h>

namespace cg = cooperative_groups;

// Problem constants: x [B=2, C=32, D=64, H=128, W=128] fp32
constexpr int B  = 2;
constexpr int C  = 32;
constexpr int DD = 64;
constexpr int HH = 128;
constexpr int WW = 128;
constexpr int HW   = HH * WW;        // 16384
constexpr int DHW  = DD * HW;        // 1048576
constexpr int NS   = B * DHW;        // 2097152 spatial sites
constexpr int NS4  = NS / 4;         // one thread handles 4 consecutive w
constexpr int DHW4 = DHW / 4;

typedef float f4 __attribute__((ext_vector_type(4)));

// =============== Fused cooperative kernel: pool -> gridsync -> conv+scale ===============
// Grid is exactly NS4 threads (2048 blocks x 256): each thread owns one f4 site.
// __launch_bounds__(256, 8) caps VGPRs at 64 so all 2048 blocks are co-resident
// (8 blocks/CU x 256 CUs) — required for the cooperative grid sync.
// NOTE: no early-return anywhere before grid.sync() (would deadlock the barrier).
__global__ __launch_bounds__(256, 8) void fused_kernel(
    const float* __restrict__ x,
    const float* __restrict__ cw,   // [2,3,3,3]
    const float* __restrict__ cb,   // [1]
    float* __restrict__ pmax,
    float* __restrict__ pavg,
    float* __restrict__ out) {
  __shared__ float wsh[54];
  __shared__ float bsh;
  if (threadIdx.x < 54) wsh[threadIdx.x] = cw[threadIdx.x];
  if (threadIdx.x == 0) bsh = cb[0];
  // grid.sync() below also block-syncs, so wsh is visible in phase 2.

  const int idx = blockIdx.x * 256 + threadIdx.x;   // < NS4 by construction
  const int b   = idx / DHW4;
  const int sp4 = idx - b * DHW4;

  // ---------------- Phase 1: channel max + mean pooling ----------------
  {
    const f4* xp = (const f4*)x + (size_t)b * C * DHW4 + sp4;
    f4 v  = xp[0];
    f4 mx = v;
    f4 sm = v;
#pragma unroll 8
    for (int c = 1; c < C; ++c) {
      f4 u = xp[(size_t)c * DHW4];
      mx.x = fmaxf(mx.x, u.x); mx.y = fmaxf(mx.y, u.y);
      mx.z = fmaxf(mx.z, u.z); mx.w = fmaxf(mx.w, u.w);
      sm += u;
    }
    ((f4*)pmax)[idx] = mx;
    ((f4*)pavg)[idx] = sm * (1.0f / (float)C);
  }

  // Device-scope visibility of pooled planes across XCDs, then grid barrier.
  __threadfence();
  cg::this_grid().sync();

  // ------- Phase 2: 3x3x3 conv (2->1 ch) + bias + sigmoid + scale x -------
  const int sp = sp4 * 4;
  const int d  = sp / HW;
  const int r  = sp - d * HW;
  const int h  = r / WW;
  const int w0 = r - h * WW;

  float acc0 = bsh, acc1 = bsh, acc2 = bsh, acc3 = bsh;

#pragma unroll
  for (int ch = 0; ch < 2; ++ch) {
    const float* p  = (ch == 0 ? pmax : pavg) + (size_t)b * DHW;
    const float* wt = wsh + ch * 27;
#pragma unroll
    for (int dd = -1; dd <= 1; ++dd) {
      int zd = d + dd;
      if (zd < 0 || zd >= DD) continue;   // zero padding
#pragma unroll
      for (int hh = -1; hh <= 1; ++hh) {
        int zh = h + hh;
        if (zh < 0 || zh >= HH) continue; // zero padding
        const float* row = p + zd * HW + zh * WW;
        const float* wr  = wt + (dd + 1) * 9 + (hh + 1) * 3;
        float v[6];
#pragma unroll
        for (int j = 0; j < 6; ++j) {
          int wj = w0 - 1 + j;
          v[j] = (wj >= 0 && wj < WW) ? row[wj] : 0.0f;
        }
#pragma unroll
        for (int t = 0; t < 3; ++t) {
          float wv = wr[t];
          acc0 = fmaf(wv, v[t],     acc0);
          acc1 = fmaf(wv, v[t + 1], acc1);
          acc2 = fmaf(wv, v[t + 2], acc2);
          acc3 = fmaf(wv, v[t + 3], acc3);
        }
      }
    }
  }

  f4 sig;
  sig.x = 1.0f / (1.0f + __expf(-acc0));
  sig.y = 1.0f / (1.0f + __expf(-acc1));
  sig.z = 1.0f / (1.0f + __expf(-acc2));
  sig.w = 1.0f / (1.0f + __expf(-acc3));

  // Stream all 32 channels: x re-read (hopefully L3-resident from phase 1),
  // out stores NONTEMPORAL so the write stream does not evict x from L3.
  const f4* xp = (const f4*)x   + (size_t)b * C * DHW4 + sp4;
  f4*       op = (f4*)out       + (size_t)b * C * DHW4 + sp4;
#pragma unroll 8
  for (int c = 0; c < C; ++c) {
    f4 v = xp[(size_t)c * DHW4];
    v *= sig;
    __builtin_nontemporal_store(v, op + (size_t)c * DHW4);
  }
}

// =============== Fallback path (round-0 structure + NT out stores) ===============
__global__ __launch_bounds__(256) void pool_kernel(
    const float* __restrict__ x,
    float* __restrict__ pmax,
    float* __restrict__ pavg) {
  int idx = blockIdx.x * 256 + threadIdx.x;
  if (idx >= NS4) return;
  int b   = idx / DHW4;
  int sp4 = idx - b * DHW4;

  const f4* xp = (const f4*)x + (size_t)b * C * DHW4 + sp4;
  f4 v  = xp[0];
  f4 mx = v;
  f4 sm = v;
#pragma unroll 8
  for (int c = 1; c < C; ++c) {
    f4 u = xp[(size_t)c * DHW4];
    mx.x = fmaxf(mx.x, u.x); mx.y = fmaxf(mx.y, u.y);
    mx.z = fmaxf(mx.z, u.z); mx.w = fmaxf(mx.w, u.w);
    sm += u;
  }
  ((f4*)pmax)[idx] = mx;
  ((f4*)pavg)[idx] = sm * (1.0f / (float)C);
}

__global__ __launch_bounds__(256) void attn_scale_kernel(
    const float* __restrict__ x,
    const float* __restrict__ pmax,
    const float* __restrict__ pavg,
    const float* __restrict__ cw,
    const float* __restrict__ cb,
    float* __restrict__ out) {
  __shared__ float wsh[54];
  __shared__ float bsh;
  if (threadIdx.x < 54) wsh[threadIdx.x] = cw[threadIdx.x];
  if (threadIdx.x == 0) bsh = cb[0];
  __syncthreads();

  int idx = blockIdx.x * 256 + threadIdx.x;
  if (idx >= NS4) return;
  int b   = idx / DHW4;
  int sp4 = idx - b * DHW4;
  int sp  = sp4 * 4;
  int d   = sp / HW;
  int r   = sp - d * HW;
  int h   = r / WW;
  int w0  = r - h * WW;

  float acc0 = bsh, acc1 = bsh, acc2 = bsh, acc3 = bsh;

#pragma unroll
  for (int ch = 0; ch < 2; ++ch) {
    const float* p  = (ch == 0 ? pmax : pavg) + (size_t)b * DHW;
    const float* wt = wsh + ch * 27;
#pragma unroll
    for (int dd = -1; dd <= 1; ++dd) {
      int zd = d + dd;
      if (zd < 0 || zd >= DD) continue;
#pragma unroll
      for (int hh = -1; hh <= 1; ++hh) {
        int zh = h + hh;
        if (zh < 0 || zh >= HH) continue;
        const float* row = p + zd * HW + zh * WW;
        const float* wr  = wt + (dd + 1) * 9 + (hh + 1) * 3;
        float v[6];
#pragma unroll
        for (int j = 0; j < 6; ++j) {
          int wj = w0 - 1 + j;
          v[j] = (wj >= 0 && wj < WW) ? row[wj] : 0.0f;
        }
#pragma unroll
        for (int t = 0; t < 3; ++t) {
          float wv = wr[t];
          acc0 = fmaf(wv, v[t],     acc0);
          acc1 = fmaf(wv, v[t + 1], acc1);
          acc2 = fmaf(wv, v[t + 2], acc2);
          acc3 = fmaf(wv, v[t + 3], acc3);
        }
      }
    }
  }

  f4 sig;
  sig.x = 1.0f / (1.0f + __expf(-acc0));
  sig.y = 1.0f / (1.0f + __expf(-acc1));
  sig.z = 1.0f / (1.0f + __expf(-acc2));
  sig.w = 1.0f / (1.0f + __expf(-acc3));

  const f4* xp = (const f4*)x   + (size_t)b * C * DHW4 + sp4;
  f4*       op = (f4*)out       + (size_t)b * C * DHW4 + sp4;
#pragma unroll 8
  for (int c = 0; c < C; ++c) {
    f4 v = xp[(size_t)c * DHW4];
    v *= sig;
    __builtin_nontemporal_store(v, op + (size_t)c * DHW4);
  }
}

extern "C" void kernel_launch(void* const* d_in, const int* in_sizes, int n_in,
                              void* d_out, int out_size, void* d_ws, size_t ws_size,
                              hipStream_t stream) {
  const float* x  = (const float*)d_in[0];
  const float* cw = (const float*)d_in[1];
  const float* cb = (const float*)d_in[2];
  float* out  = (float*)d_out;
  float* pmax = (float*)d_ws;          // NS floats (8 MiB)
  float* pavg = pmax + NS;             // NS floats (8 MiB)

  dim3 blk(256);
  dim3 grid(NS4 / 256);                // 2048 blocks, exact

  void* args[] = {(void*)&x, (void*)&cw, (void*)&cb,
                  (void*)&pmax, (void*)&pavg, (void*)&out};
  hipError_t err = hipLaunchCooperativeKernel((const void*)fused_kernel,
                                              grid, blk, args, 0, stream);
  if (err != hipSuccess) {
    // Cooperative launch unavailable (capture/occupancy) — two-kernel fallback.
    pool_kernel<<<grid, blk, 0, stream>>>(x, pmax, pavg);
    attn_scale_kernel<<<grid, blk, 0, stream>>>(x, pmax, pavg, cw, cb, out);
  }
}

// Round 3
// 533.201 us; speedup vs baseline: 2.0503x; 2.0503x over previous
//
#include <hip/hip_runtime.h>
#include <math.h>

// Problem constants: x [B=2, C=32, D=64, H=128, W=128] fp32
constexpr int B  = 2;
constexpr int C  = 32;
constexpr int DD = 64;
constexpr int HH = 128;
constexpr int WW = 128;
constexpr int HW   = HH * WW;        // 16384
constexpr int DHW  = DD * HW;        // 1048576
constexpr int NS   = B * DHW;        // 2097152 spatial sites
constexpr int NS4  = NS / 4;         // one thread handles 4 consecutive w
constexpr int DHW4 = DHW / 4;

typedef float f4 __attribute__((ext_vector_type(4)));

// ---------------- Pass 1: channel max + mean pooling ----------------
// Each thread owns 4 consecutive w positions (float4), loops over C=32
// channels. Reads fully coalesced; x streams through L3 and (mostly)
// stays resident for pass 2's re-read.
// NOTE: no __launch_bounds__ min-waves — round 2 proved forcing 8 wg/CU
// crushes VGPRs to 28 and serializes every load (0.73 TB/s).
__global__ __launch_bounds__(256) void pool_kernel(
    const float* __restrict__ x,
    float* __restrict__ pmax,
    float* __restrict__ pavg) {
  int idx = blockIdx.x * 256 + threadIdx.x;
  if (idx >= NS4) return;
  int b   = idx / DHW4;
  int sp4 = idx - b * DHW4;

  const f4* xp = (const f4*)x + (size_t)b * C * DHW4 + sp4;
  f4 v  = xp[0];
  f4 mx = v;
  f4 sm = v;
#pragma unroll 8
  for (int c = 1; c < C; ++c) {
    f4 u = xp[(size_t)c * DHW4];
    mx.x = fmaxf(mx.x, u.x); mx.y = fmaxf(mx.y, u.y);
    mx.z = fmaxf(mx.z, u.z); mx.w = fmaxf(mx.w, u.w);
    sm += u;
  }
  ((f4*)pmax)[idx] = mx;                 // idx == b*DHW4 + sp4
  ((f4*)pavg)[idx] = sm * (1.0f / (float)C);
}

// ------- Pass 2: 3x3x3 conv (2->1 ch) + bias + sigmoid + scale x -------
// Stencil reads of the 32 MiB pooled planes hit L2/L3. x re-read should
// hit L3 (populated by pass 1 — round 2's fused kernel measured FETCH =
// 277 MB, proving ~95% reuse). out stores are NONTEMPORAL so the 268 MB
// write stream does not evict x from L3 mid-pass.
__global__ __launch_bounds__(256) void attn_scale_kernel(
    const float* __restrict__ x,
    const float* __restrict__ pmax,
    const float* __restrict__ pavg,
    const float* __restrict__ cw,   // [2,3,3,3] (out ch dim = 1)
    const float* __restrict__ cb,   // [1]
    float* __restrict__ out) {
  __shared__ float wsh[54];
  __shared__ float bsh;
  if (threadIdx.x < 54) wsh[threadIdx.x] = cw[threadIdx.x];
  if (threadIdx.x == 0) bsh = cb[0];
  __syncthreads();

  int idx = blockIdx.x * 256 + threadIdx.x;
  if (idx >= NS4) return;
  int b   = idx / DHW4;
  int sp4 = idx - b * DHW4;
  int sp  = sp4 * 4;
  int d   = sp / HW;
  int r   = sp - d * HW;
  int h   = r / WW;
  int w0  = r - h * WW;

  float acc0 = bsh, acc1 = bsh, acc2 = bsh, acc3 = bsh;

#pragma unroll
  for (int ch = 0; ch < 2; ++ch) {
    const float* p  = (ch == 0 ? pmax : pavg) + (size_t)b * DHW;
    const float* wt = wsh + ch * 27;
#pragma unroll
    for (int dd = -1; dd <= 1; ++dd) {
      int zd = d + dd;
      if (zd < 0 || zd >= DD) continue;   // zero padding
#pragma unroll
      for (int hh = -1; hh <= 1; ++hh) {
        int zh = h + hh;
        if (zh < 0 || zh >= HH) continue; // zero padding
        const float* row = p + zd * HW + zh * WW;
        const float* wr  = wt + (dd + 1) * 9 + (hh + 1) * 3;
        float v[6];
#pragma unroll
        for (int j = 0; j < 6; ++j) {
          int wj = w0 - 1 + j;
          v[j] = (wj >= 0 && wj < WW) ? row[wj] : 0.0f;
        }
#pragma unroll
        for (int t = 0; t < 3; ++t) {
          float wv = wr[t];
          acc0 = fmaf(wv, v[t],     acc0);
          acc1 = fmaf(wv, v[t + 1], acc1);
          acc2 = fmaf(wv, v[t + 2], acc2);
          acc3 = fmaf(wv, v[t + 3], acc3);
        }
      }
    }
  }

  f4 sig;
  sig.x = 1.0f / (1.0f + __expf(-acc0));
  sig.y = 1.0f / (1.0f + __expf(-acc1));
  sig.z = 1.0f / (1.0f + __expf(-acc2));
  sig.w = 1.0f / (1.0f + __expf(-acc3));

  const f4* xp = (const f4*)x   + (size_t)b * C * DHW4 + sp4;
  f4*       op = (f4*)out       + (size_t)b * C * DHW4 + sp4;
#pragma unroll 8
  for (int c = 0; c < C; ++c) {
    f4 v = xp[(size_t)c * DHW4];
    v *= sig;
    __builtin_nontemporal_store(v, op + (size_t)c * DHW4);
  }
}

extern "C" void kernel_launch(void* const* d_in, const int* in_sizes, int n_in,
                              void* d_out, int out_size, void* d_ws, size_t ws_size,
                              hipStream_t stream) {
  const float* x  = (const float*)d_in[0];
  const float* cw = (const float*)d_in[1];
  const float* cb = (const float*)d_in[2];
  float* out  = (float*)d_out;
  float* pmax = (float*)d_ws;          // NS floats (8 MiB)
  float* pavg = pmax + NS;             // NS floats (8 MiB)

  dim3 blk(256);
  dim3 grid((NS4 + 255) / 256);        // 2048 blocks
  pool_kernel<<<grid, blk, 0, stream>>>(x, pmax, pavg);
  attn_scale_kernel<<<grid, blk, 0, stream>>>(x, pmax, pavg, cw, cb, out);
}

// Round 4
// 524.912 us; speedup vs baseline: 2.0826x; 1.0158x over previous
//
#include <hip/hip_runtime.h>
#include <math.h>

// Problem constants: x [B=2, C=32, D=64, H=128, W=128] fp32
constexpr int B  = 2;
constexpr int C  = 32;
constexpr int DD = 64;
constexpr int HH = 128;
constexpr int WW = 128;
constexpr int HW   = HH * WW;        // 16384
constexpr int DHW  = DD * HW;        // 1048576
constexpr int NS   = B * DHW;        // 2097152 spatial sites
constexpr int NS4  = NS / 4;         // one thread handles 4 consecutive w
constexpr int DHW4 = DHW / 4;

typedef float f4 __attribute__((ext_vector_type(4)));
typedef float f2 __attribute__((ext_vector_type(2)));

// ---------------- Pass 1: channel max + mean pooling ----------------
// Writes pooled planes INTERLEAVED: pooled[site] = float2(max, avg).
// Same bytes as two planes, but pass 2's stencil then needs half the
// loads and half the cache lines. Reads of x fully coalesced; x streams
// through L3 and stays resident for pass 2's re-read (round-2 evidence:
// fused-kernel FETCH was 277 MB ≈ x fetched once).
// NOTE: no min-waves launch bound — round 2 proved forcing 8 wg/CU
// crushes VGPRs to 28 and serializes every load (0.73 TB/s).
__global__ __launch_bounds__(256) void pool_kernel(
    const float* __restrict__ x,
    float* __restrict__ pooled) {      // NS float2 (16 MiB)
  int idx = blockIdx.x * 256 + threadIdx.x;
  if (idx >= NS4) return;
  int b   = idx / DHW4;
  int sp4 = idx - b * DHW4;

  const f4* xp = (const f4*)x + (size_t)b * C * DHW4 + sp4;
  f4 v  = xp[0];
  f4 mx = v;
  f4 sm = v;
#pragma unroll 8
  for (int c = 1; c < C; ++c) {
    f4 u = xp[(size_t)c * DHW4];
    mx.x = fmaxf(mx.x, u.x); mx.y = fmaxf(mx.y, u.y);
    mx.z = fmaxf(mx.z, u.z); mx.w = fmaxf(mx.w, u.w);
    sm += u;
  }
  f4 av = sm * (1.0f / (float)C);

  // global site s = 4*idx; pooled f4-index = s*8B/16B = 2*idx
  f4 lo = {mx.x, av.x, mx.y, av.y};
  f4 hi = {mx.z, av.z, mx.w, av.w};
  f4* pp = (f4*)pooled + (size_t)idx * 2;
  pp[0] = lo;
  pp[1] = hi;
}

// ------- Pass 2: 3x3x3 conv (2->1 ch) + bias + sigmoid + scale x -------
// Stencil reads the interleaved pooled plane (L1/L2-resident): 54 float2
// loads per thread instead of 108 scalar loads over two planes. x re-read
// hits L3 (populated by pass 1); out stores NONTEMPORAL so the 268 MB
// write stream does not evict x from L3 mid-pass.
__global__ __launch_bounds__(256) void attn_scale_kernel(
    const float* __restrict__ x,
    const float* __restrict__ pooled,  // float2(max, avg) per site
    const float* __restrict__ cw,      // [2,3,3,3] (out ch dim = 1)
    const float* __restrict__ cb,      // [1]
    float* __restrict__ out) {
  __shared__ float wsh[54];            // [0..26]=max-ch wts, [27..53]=avg-ch
  __shared__ float bsh;
  if (threadIdx.x < 54) wsh[threadIdx.x] = cw[threadIdx.x];
  if (threadIdx.x == 0) bsh = cb[0];
  __syncthreads();

  int idx = blockIdx.x * 256 + threadIdx.x;
  if (idx >= NS4) return;
  int b   = idx / DHW4;
  int sp4 = idx - b * DHW4;
  int sp  = sp4 * 4;
  int d   = sp / HW;
  int r   = sp - d * HW;
  int h   = r / WW;
  int w0  = r - h * WW;

  float acc0 = bsh, acc1 = bsh, acc2 = bsh, acc3 = bsh;

  const f2* pb = (const f2*)pooled + (size_t)b * DHW;

#pragma unroll
  for (int dd = -1; dd <= 1; ++dd) {
    int zd = d + dd;
    if (zd < 0 || zd >= DD) continue;   // zero padding
#pragma unroll
    for (int hh = -1; hh <= 1; ++hh) {
      int zh = h + hh;
      if (zh < 0 || zh >= HH) continue; // zero padding
      const f2* row = pb + (size_t)zd * HW + zh * WW;
      const float* wm = wsh + (dd + 1) * 9 + (hh + 1) * 3;  // max-ch taps
      const float* wa = wm + 27;                            // avg-ch taps
      f2 v[6];
#pragma unroll
      for (int j = 0; j < 6; ++j) {
        int wj = w0 - 1 + j;
        f2 z; z.x = 0.0f; z.y = 0.0f;
        v[j] = (wj >= 0 && wj < WW) ? row[wj] : z;
      }
#pragma unroll
      for (int t = 0; t < 3; ++t) {
        float m = wm[t], a = wa[t];
        acc0 = fmaf(m, v[t].x,     fmaf(a, v[t].y,     acc0));
        acc1 = fmaf(m, v[t + 1].x, fmaf(a, v[t + 1].y, acc1));
        acc2 = fmaf(m, v[t + 2].x, fmaf(a, v[t + 2].y, acc2));
        acc3 = fmaf(m, v[t + 3].x, fmaf(a, v[t + 3].y, acc3));
      }
    }
  }

  f4 sig;
  sig.x = 1.0f / (1.0f + __expf(-acc0));
  sig.y = 1.0f / (1.0f + __expf(-acc1));
  sig.z = 1.0f / (1.0f + __expf(-acc2));
  sig.w = 1.0f / (1.0f + __expf(-acc3));

  const f4* xp = (const f4*)x   + (size_t)b * C * DHW4 + sp4;
  f4*       op = (f4*)out       + (size_t)b * C * DHW4 + sp4;
#pragma unroll 8
  for (int c = 0; c < C; ++c) {
    f4 v = xp[(size_t)c * DHW4];
    v *= sig;
    __builtin_nontemporal_store(v, op + (size_t)c * DHW4);
  }
}

extern "C" void kernel_launch(void* const* d_in, const int* in_sizes, int n_in,
                              void* d_out, int out_size, void* d_ws, size_t ws_size,
                              hipStream_t stream) {
  const float* x  = (const float*)d_in[0];
  const float* cw = (const float*)d_in[1];
  const float* cb = (const float*)d_in[2];
  float* out    = (float*)d_out;
  float* pooled = (float*)d_ws;        // NS float2 (16 MiB)

  dim3 blk(256);
  dim3 grid((NS4 + 255) / 256);        // 2048 blocks
  pool_kernel<<<grid, blk, 0, stream>>>(x, pooled);
  attn_scale_kernel<<<grid, blk, 0, stream>>>(x, pooled, cw, cb, out);
}

// Round 5
// 504.395 us; speedup vs baseline: 2.1673x; 1.0407x over previous
//
#include <hip/hip_runtime.h>
#include <math.h>

// Problem constants: x [B=2, C=32, D=64, H=128, W=128] fp32
constexpr int B  = 2;
constexpr int C  = 32;
constexpr int DD = 64;
constexpr int HH = 128;
constexpr int WW = 128;
constexpr int HW   = HH * WW;        // 16384
constexpr int DHW  = DD * HW;        // 1048576
constexpr int NS   = B * DHW;        // 2097152 spatial sites
constexpr int NS4  = NS / 4;         // f4 site-groups
constexpr int DHW4 = DHW / 4;        // 262144

// Grid: 1024 blocks x 256 threads; each thread owns TWO f4 site-groups
// (base, base+256) so every channel visit per block is an 8-KB contiguous
// burst instead of 4-KB (HBM row-buffer friendliness). 1024*512 = NS4 exact;
// blocks never straddle the b boundary (262144 = 512*512).
constexpr int NBLK = NS4 / 512;      // 1024

typedef float f4 __attribute__((ext_vector_type(4)));
typedef float f2 __attribute__((ext_vector_type(2)));

// XCD-chunked bijective swizzle (NBLK % 8 == 0): consecutive swizzled ids
// stay on ONE XCD -> each XCD's L2/HBM sees large contiguous runs per
// channel stream, and pool's pooled-slice producer XCD == attn's consumer.
__device__ inline int xcd_swz(int bid) {
  return (bid & 7) * (NBLK / 8) + (bid >> 3);
}

// ---------------- Pass 1: channel max + mean pooling ----------------
// pooled[site] = float2(max, avg) interleaved (round-4 win: halves the
// stencil loads in pass 2).
// NOTE: no min-waves launch bound — round 2 proved forcing 8 wg/CU
// crushes VGPRs to 28 and serializes every load (0.73 TB/s).
__global__ __launch_bounds__(256) void pool_kernel(
    const float* __restrict__ x,
    float* __restrict__ pooled) {      // NS float2 (16 MiB)
  const int bid  = xcd_swz(blockIdx.x);
  const int idxA = bid * 512 + threadIdx.x;   // f4-group A
  const int idxB = idxA + 256;                // f4-group B (same b)
  const int b    = idxA / DHW4;
  const int spA  = idxA - b * DHW4;
  const int spB  = spA + 256;

  const f4* xp = (const f4*)x + (size_t)b * C * DHW4;
  f4 uA = xp[spA], uB = xp[spB];
  f4 mxA = uA, smA = uA;
  f4 mxB = uB, smB = uB;
#pragma unroll 4
  for (int c = 1; c < C; ++c) {
    f4 a = xp[(size_t)c * DHW4 + spA];
    f4 bb = xp[(size_t)c * DHW4 + spB];
    mxA.x = fmaxf(mxA.x, a.x);  mxA.y = fmaxf(mxA.y, a.y);
    mxA.z = fmaxf(mxA.z, a.z);  mxA.w = fmaxf(mxA.w, a.w);
    smA += a;
    mxB.x = fmaxf(mxB.x, bb.x); mxB.y = fmaxf(mxB.y, bb.y);
    mxB.z = fmaxf(mxB.z, bb.z); mxB.w = fmaxf(mxB.w, bb.w);
    smB += bb;
  }
  const float inv = 1.0f / (float)C;
  f4 avA = smA * inv, avB = smB * inv;

  f4* pp = (f4*)pooled;
  f4 loA = {mxA.x, avA.x, mxA.y, avA.y};
  f4 hiA = {mxA.z, avA.z, mxA.w, avA.w};
  f4 loB = {mxB.x, avB.x, mxB.y, avB.y};
  f4 hiB = {mxB.z, avB.z, mxB.w, avB.w};
  pp[(size_t)idxA * 2]     = loA;
  pp[(size_t)idxA * 2 + 1] = hiA;
  pp[(size_t)idxB * 2]     = loB;
  pp[(size_t)idxB * 2 + 1] = hiB;
}

// Per-site-group conv(3x3x3, 2ch interleaved) + bias + sigmoid.
__device__ inline f4 conv_sig(const f2* __restrict__ pb,
                              const float* __restrict__ wsh,
                              float bias, int sp) {
  const int d  = sp / HW;
  const int r  = sp - d * HW;
  const int h  = r / WW;
  const int w0 = r - h * WW;

  float acc0 = bias, acc1 = bias, acc2 = bias, acc3 = bias;

#pragma unroll
  for (int dd = -1; dd <= 1; ++dd) {
    int zd = d + dd;
    if (zd < 0 || zd >= DD) continue;   // zero padding
#pragma unroll
    for (int hh = -1; hh <= 1; ++hh) {
      int zh = h + hh;
      if (zh < 0 || zh >= HH) continue; // zero padding
      const f2* row = pb + (size_t)zd * HW + zh * WW;
      const float* wm = wsh + (dd + 1) * 9 + (hh + 1) * 3;  // max-ch taps
      const float* wa = wm + 27;                            // avg-ch taps
      f2 v[6];
#pragma unroll
      for (int j = 0; j < 6; ++j) {
        int wj = w0 - 1 + j;
        f2 z; z.x = 0.0f; z.y = 0.0f;
        v[j] = (wj >= 0 && wj < WW) ? row[wj] : z;
      }
#pragma unroll
      for (int t = 0; t < 3; ++t) {
        float m = wm[t], a = wa[t];
        acc0 = fmaf(m, v[t].x,     fmaf(a, v[t].y,     acc0));
        acc1 = fmaf(m, v[t + 1].x, fmaf(a, v[t + 1].y, acc1));
        acc2 = fmaf(m, v[t + 2].x, fmaf(a, v[t + 2].y, acc2));
        acc3 = fmaf(m, v[t + 3].x, fmaf(a, v[t + 3].y, acc3));
      }
    }
  }

  f4 sig;
  sig.x = 1.0f / (1.0f + __expf(-acc0));
  sig.y = 1.0f / (1.0f + __expf(-acc1));
  sig.z = 1.0f / (1.0f + __expf(-acc2));
  sig.w = 1.0f / (1.0f + __expf(-acc3));
  return sig;
}

// ------- Pass 2: conv + bias + sigmoid + scale x (streaming) -------
// x re-read hits L3 (round-2 evidence: fused FETCH = 277 MB ~ x once);
// out stores NONTEMPORAL so the write stream doesn't evict x from L3.
__global__ __launch_bounds__(256) void attn_scale_kernel(
    const float* __restrict__ x,
    const float* __restrict__ pooled,  // float2(max, avg) per site
    const float* __restrict__ cw,      // [2,3,3,3]
    const float* __restrict__ cb,      // [1]
    float* __restrict__ out) {
  __shared__ float wsh[54];            // [0..26]=max-ch wts, [27..53]=avg-ch
  __shared__ float bsh;
  if (threadIdx.x < 54) wsh[threadIdx.x] = cw[threadIdx.x];
  if (threadIdx.x == 0) bsh = cb[0];
  __syncthreads();

  const int bid  = xcd_swz(blockIdx.x);
  const int idxA = bid * 512 + threadIdx.x;
  const int idxB = idxA + 256;
  const int b    = idxA / DHW4;
  const int spA  = idxA - b * DHW4;
  const int spB  = spA + 256;

  const f2* pb = (const f2*)pooled + (size_t)b * DHW;
  f4 sigA = conv_sig(pb, wsh, bsh, spA * 4);
  f4 sigB = conv_sig(pb, wsh, bsh, spB * 4);

  const f4* xp = (const f4*)x   + (size_t)b * C * DHW4;
  f4*       op = (f4*)out       + (size_t)b * C * DHW4;
#pragma unroll 4
  for (int c = 0; c < C; ++c) {
    f4 vA = xp[(size_t)c * DHW4 + spA];
    f4 vB = xp[(size_t)c * DHW4 + spB];
    vA *= sigA;
    vB *= sigB;
    __builtin_nontemporal_store(vA, op + (size_t)c * DHW4 + spA);
    __builtin_nontemporal_store(vB, op + (size_t)c * DHW4 + spB);
  }
}

extern "C" void kernel_launch(void* const* d_in, const int* in_sizes, int n_in,
                              void* d_out, int out_size, void* d_ws, size_t ws_size,
                              hipStream_t stream) {
  const float* x  = (const float*)d_in[0];
  const float* cw = (const float*)d_in[1];
  const float* cb = (const float*)d_in[2];
  float* out    = (float*)d_out;
  float* pooled = (float*)d_ws;        // NS float2 (16 MiB)

  dim3 blk(256);
  dim3 grid(NBLK);                     // 1024 blocks, exact
  pool_kernel<<<grid, blk, 0, stream>>>(x, pooled);
  attn_scale_kernel<<<grid, blk, 0, stream>>>(x, pooled, cw, cb, out);
}